// Round 10
// baseline (603.099 us; speedup 1.0000x reference)
//
#include <hip/hip_runtime.h>
#include <cmath>
#include <cstdint>

#define NNODES 512
#define NEDGES 2048

typedef _Float16 half2v __attribute__((ext_vector_type(2)));

// ---- workspace layout (float offsets) ----
#define OFF_W3J   0
#define OFF_SH    512
#define OFF_H1    (OFF_SH + NEDGES*9)
#define OFF_H2    (OFF_H1 + NEDGES*6)
#define OFF_H3    (OFF_H2 + NEDGES*6)
#define OFF_W2P1  (OFF_H3 + NEDGES*6)           // split: W1p (384*768); !split: r-major pack
#define OFF_W2P2  (OFF_W2P1 + 6*49152)
#define OFF_W2P3  (OFF_W2P2 + 6*90112)
#define OFF_XH    (OFF_W2P3 + 6*22528)
#define OFF_XB    (OFF_XH + NNODES*576)
#define OFF_MSGA  (OFF_XB + NNODES*1152)
#define OFF_CNT   (OFF_MSGA + NEDGES*576)
#define OFF_COFF  (OFF_CNT + 512)
#define OFF_LIST  (OFF_COFF + 1024)
#define OFF_RANK  (OFF_LIST + 2048)
#define OFF_MSGB  (OFF_RANK + 2048)             // split: also V
#define WS_NEED_SPLIT ((size_t)(OFF_MSGB + NEDGES*576) * 4)

// instruction tables (order matches reference tp_instructions for in_ls=[0,1,2])
constexpr int IL1[11]={0,0,0,1,1,1,1,2,2,2,2};
constexpr int IL2[11]={0,1,2,0,1,1,2,0,1,2,2};
constexpr int IL3[11]={0,1,2,1,0,2,1,2,1,0,2};
constexpr int IW3O[11]={0,1,10,35,44,53,98,143,168,213,238};
constexpr int IKOFF[3]={0,1,4};
constexpr int IFANM[3]={3,4,4};

// ---------- helpers ----------
__device__ __forceinline__ unsigned int packh2f(float a, float b){
  half2v h; h.x=(_Float16)a; h.y=(_Float16)b;
  return __builtin_bit_cast(unsigned int, h);
}
__device__ __forceinline__ half2v u2h2(unsigned int u){ return __builtin_bit_cast(half2v, u); }
__device__ __forceinline__ float dot2f(unsigned int a, unsigned int b, float c){
#if __has_builtin(__builtin_amdgcn_fdot2)
  return __builtin_amdgcn_fdot2(u2h2(a), u2h2(b), c, false);
#else
  half2v ha=u2h2(a), hb=u2h2(b);
  return c + (float)ha.x*(float)hb.x + (float)ha.y*(float)hb.y;
#endif
}
__device__ __forceinline__ unsigned int pk2(float a, float b){
#if __has_builtin(__builtin_amdgcn_cvt_pkrtz)
  auto h=__builtin_amdgcn_cvt_pkrtz(a,b);
  return __builtin_bit_cast(unsigned int,h);
#else
  return packh2f(a,b);
#endif
}
__device__ __forceinline__ unsigned short f2h(float f){
  _Float16 h=(_Float16)f; return __builtin_bit_cast(unsigned short,h);
}
__device__ __forceinline__ float softplusf(float v){ return fmaxf(v,0.f)+log1pf(expf(-fabsf(v))); }

// ================= W3J (fp64, on device) =================
__device__ double dfact(int n){ double f=1.0; for(int i=2;i<=n;++i) f*=(double)i; return f; }

__device__ double w3j_c_dev(int l1,int l2,int l3,int m1,int m2,int m3){
  if (m1+m2+m3 != 0) return 0.0;
  int p = l1 - l2 - m3;
  double sign = (((p%2)+2)%2) ? -1.0 : 1.0;
  double pref = sign*sqrt(dfact(l1+l2-l3)*dfact(l1-l2+l3)*dfact(-l1+l2+l3)/dfact(l1+l2+l3+1)
              *dfact(l1+m1)*dfact(l1-m1)*dfact(l2+m2)*dfact(l2-m2)*dfact(l3+m3)*dfact(l3-m3));
  double s=0.0;
  for (int t=0;t<=l1+l2-l3;++t){
    int d0=t, d1v=l3-l2+t+m1, d2v=l3-l1+t-m2, d3v=l1+l2-l3-t, d4=l1-t-m1, d5=l2-t+m2;
    if (d0<0||d1v<0||d2v<0||d3v<0||d4<0||d5<0) continue;
    double den=dfact(d0)*dfact(d1v)*dfact(d2v)*dfact(d3v)*dfact(d4)*dfact(d5);
    s += ((t&1)?-1.0:1.0)/den;
  }
  return pref*s;
}

__device__ void u_real_dev(int l, double Ur[5][5], double Ui[5][5]){
  for(int a=0;a<5;++a)for(int b=0;b<5;++b){Ur[a][b]=0.0;Ui[a][b]=0.0;}
  Ur[l][l]=1.0;
  double inv2 = 1.0/sqrt(2.0);
  for(int m=1;m<=l;++m){
    double sgn = (m&1)?-1.0:1.0;
    Ur[l+m][l+m] = sgn*inv2;
    Ur[l+m][l-m] = inv2;
    Ui[l-m][l-m] = inv2;
    Ui[l-m][l+m] = -sgn*inv2;
  }
}

__global__ void w3j_kernel(float* __restrict__ out){
  const int L1[11]={0,0,0,1,1,1,1,2,2,2,2};
  const int L2[11]={0,1,2,0,1,1,2,0,1,2,2};
  const int L3[11]={0,1,2,1,0,2,1,2,1,0,2};
  const int OFF[11]={0,1,10,35,44,53,98,143,168,213,238};
  int t = blockIdx.x;
  int tid = threadIdx.x;
  int l1=L1[t], l2=L2[t], l3=L3[t];
  int d1=2*l1+1, d2=2*l2+1, d3=2*l3+1;
  int sz=d1*d2*d3;
  __shared__ double Wt[125];
  __shared__ double U1r[5][5],U1i[5][5],U2r[5][5],U2i[5][5],U3r[5][5],U3i[5][5];
  __shared__ double Cv[125];
  __shared__ double red[128];
  for(int idx=tid; idx<sz; idx+=128){
    int a=idx/(d2*d3), rem=idx%(d2*d3), b=rem/d3, c=rem%d3;
    Wt[idx]=w3j_c_dev(l1,l2,l3,a-l1,b-l2,c-l3);
  }
  if(tid==0) u_real_dev(l1,U1r,U1i);
  if(tid==1) u_real_dev(l2,U2r,U2i);
  if(tid==2) u_real_dev(l3,U3r,U3i);
  __syncthreads();
  for(int idx=tid; idx<sz; idx+=128){
    int a=idx/(d2*d3), rem=idx%(d2*d3), b=rem/d3, c=rem%d3;
    double cr=0.0, ci=0.0;
    for(int m=0;m<d1;++m)for(int n=0;n<d2;++n){
      double t2r = U1r[a][m]*U2r[b][n]-U1i[a][m]*U2i[b][n];
      double t2i = U1r[a][m]*U2i[b][n]+U1i[a][m]*U2r[b][n];
      if (t2r==0.0 && t2i==0.0) continue;
      for(int o=0;o<d3;++o){
        double wv=Wt[(m*d2+n)*d3+o];
        if (wv==0.0) continue;
        double t3r=t2r*U3r[c][o]-t2i*U3i[c][o];
        double t3i=t2r*U3i[c][o]+t2i*U3r[c][o];
        cr += t3r*wv; ci += t3i*wv;
      }
    }
    Cv[idx]=cr+ci;
  }
  __syncthreads();
  double s=0.0;
  for(int idx=tid; idx<sz; idx+=128) s+=Cv[idx]*Cv[idx];
  red[tid]=s; __syncthreads();
  for(int d=64; d>0; d>>=1){ if(tid<d) red[tid]+=red[tid+d]; __syncthreads(); }
  double nrm = sqrt(red[0]);
  double inv = (nrm>0.0)?1.0/nrm:0.0;
  for(int idx=tid; idx<sz; idx+=128) out[OFF[t]+idx]=(float)(Cv[idx]*inv);
}

// ================= Edge prep =================
__global__ void edge_prep_kernel(const float* __restrict__ pos, const int* __restrict__ ei,
    const float* __restrict__ rw1a, const float* __restrict__ rw1b, const float* __restrict__ rw1c,
    float* __restrict__ sh, unsigned int* __restrict__ h1, unsigned int* __restrict__ h2,
    unsigned int* __restrict__ h3){
  int e = blockIdx.x*blockDim.x+threadIdx.x;
  if (e>=NEDGES) return;
  int s = ei[e], d = ei[NEDGES+e];
  float vx=pos[3*s]-pos[3*d], vy=pos[3*s+1]-pos[3*d+1], vz=pos[3*s+2]-pos[3*d+2];
  float dist=sqrtf(vx*vx+vy*vy+vz*vz);
  float dm = fmaxf(dist,1e-12f);
  float x=vx/dm, y=vy/dm, z=vz/dm;
  const float s3=sqrtf(3.f), s15=sqrtf(15.f), s5=sqrtf(5.f);
  float shv[9];
  shv[0]=1.f; shv[1]=s3*y; shv[2]=s3*z; shv[3]=s3*x;
  shv[4]=s15*x*y; shv[5]=s15*y*z; shv[6]=0.5f*s5*(3.f*z*z-1.f); shv[7]=s15*x*z; shv[8]=0.5f*s15*(x*x-y*y);
  #pragma unroll
  for(int i=0;i<9;++i) sh[e*9+i]=shv[i];
  float rb[11];
  #pragma unroll
  for(int i=0;i<11;++i){ float diff=(dist-0.8f*(float)i)*(1.f/0.8f); rb[i]=expf(-diff*diff)*(1.f/1.12f); }
  const float c1 = 1.f/sqrtf(11.f);
  const float c2 = sqrtf(2.f)/sqrtf(12.f);
  const float* rws[3]={rw1a,rw1b,rw1c};
  unsigned int* outs[3]={h1,h2,h3};
  for(int L=0;L<3;++L){
    float hv[12];
    #pragma unroll
    for(int r=0;r<12;++r){
      float t=0.f;
      #pragma unroll
      for(int k=0;k<11;++k) t+=rb[k]*rws[L][k*12+r];
      t*=c1;
      hv[r]=fmaxf(t,0.f)*c2;
    }
    #pragma unroll
    for(int r2=0;r2<6;++r2) outs[L][e*6+r2]=packh2f(hv[2*r2],hv[2*r2+1]);
  }
}

// ================= W2 fp32 -> packed f16 pairs (r-major, proven layout) =================
__global__ void w2pack_kernel(const float* __restrict__ w2, unsigned int* __restrict__ out, int nW){
  int idx=blockIdx.x*256+threadIdx.x;
  if(idx>=6*nW) return;
  int r2=idx/nW, c=idx-r2*nW;
  out[idx]=packh2f(w2[(size_t)(2*r2)*nW+c], w2[(size_t)(2*r2+1)*nW+c]);
}

// ===== layer-1 W pack (split path, node-side GEMM) =====
__global__ void w1pack_kernel(const float* __restrict__ w2, unsigned int* __restrict__ out){
  int idx=blockIdx.x*256+threadIdx.x;
  if(idx>=384*768) return;
  int col=idx/768, rem=idx-col*768;
  int r=rem/64, u2=rem-r*64;
  int i=col>>7, w=col&127;
  size_t s0=(size_t)r*49152 + i*16384 + (2*u2)*128 + w;
  out[idx]=packh2f(w2[s0], w2[s0+128]);
}

// ===== layer-1 node-side GEMM =====
__global__ __launch_bounds__(384) void vgemm1_kernel(const unsigned int* __restrict__ xh,
    const unsigned int* __restrict__ w1p, unsigned int* __restrict__ V){
  __shared__ __align__(16) unsigned int s_x[4][64];
  int tid=threadIdx.x;
  int n0=blockIdx.x*4;
  for(int ix=tid; ix<256; ix+=384){ int n=ix>>6, u2=ix&63; s_x[n][u2]=xh[(size_t)(n0+n)*64+u2]; }
  __syncthreads();
  int col=tid;
  float acc[4][12];
  #pragma unroll
  for(int n=0;n<4;++n)
    #pragma unroll
    for(int r=0;r<12;++r) acc[n][r]=0.f;
  const uint4* Wp=(const uint4*)(w1p + (size_t)col*768);
  for(int u4=0;u4<16;++u4){
    uint4 xv[4];
    #pragma unroll
    for(int n=0;n<4;++n) xv[n]=((const uint4*)s_x[n])[u4];
    #pragma unroll
    for(int r=0;r<12;++r){
      uint4 wv=Wp[r*16+u4];
      #pragma unroll
      for(int n=0;n<4;++n){
        acc[n][r]=dot2f(xv[n].x,wv.x,acc[n][r]);
        acc[n][r]=dot2f(xv[n].y,wv.y,acc[n][r]);
        acc[n][r]=dot2f(xv[n].z,wv.z,acc[n][r]);
        acc[n][r]=dot2f(xv[n].w,wv.w,acc[n][r]);
      }
    }
  }
  #pragma unroll
  for(int n=0;n<4;++n)
    #pragma unroll
    for(int r2=0;r2<6;++r2)
      V[((size_t)(n0+n)*384+col)*6+r2]=pk2(acc[n][2*r2],acc[n][2*r2+1]);
}

// ===== layer-1 edge pass =====
__global__ __launch_bounds__(384) void conv1_edge_kernel(const unsigned int* __restrict__ V,
    const unsigned int* __restrict__ h1, const float* __restrict__ shb,
    const int* __restrict__ dstp, const float* __restrict__ w3j,
    unsigned int* __restrict__ msgA){
  const int W3O[3]={0,1,10};
  unsigned short* m16=(unsigned short*)msgA;
  int tid=threadIdx.x;
  int col=tid;
  int i=col>>7, w=col&127;
  int d3=2*i+1;
  float alpha=sqrtf((float)(2*i+1))*(1.f/sqrtf(128.f));
  int e0=blockIdx.x*2;
  #pragma unroll
  for(int s=0;s<2;++s){
    int e=e0+s;
    int n=dstp[e];
    const unsigned int* vp=V+((size_t)n*384+col)*6;
    float G=0.f;
    #pragma unroll
    for(int r2=0;r2<6;++r2) G=dot2f(h1[(size_t)e*6+r2], vp[r2], G);
    int base=(i==0)?0:((i==1)?128:512);
    for(int k=0;k<d3;++k){
      float B=0.f;
      for(int j=0;j<d3;++j) B += shb[(size_t)e*9+i*i+j]*w3j[W3O[i]+j*d3+k];
      m16[(size_t)e*1152 + base + w*d3 + k]=f2h(G*B*alpha);
    }
  }
}

// ================= CSR build: rank -> scan -> scatter =================
__global__ __launch_bounds__(256) void csr_rank_kernel(const int* __restrict__ src,
    int* __restrict__ cnt, int* __restrict__ rankA){
  __shared__ int s_src[NEDGES];
  int tid=threadIdx.x;
  int4* s4=(int4*)s_src;
  const int4* g4=(const int4*)src;
  for(int i=tid;i<NEDGES/4;i+=256) s4[i]=g4[i];
  __syncthreads();
  int e=blockIdx.x*256+tid;
  int s=s_src[e];
  int lt=0, tot=0;
  for(int b=0;b<NEDGES/4;b+=8){
    int4 v[8];
    #pragma unroll
    for(int k=0;k<8;++k) v[k]=s4[b+k];
    #pragma unroll
    for(int k=0;k<8;++k){
      int j0=4*(b+k);
      tot += ((v[k].x==s)?1:0)+((v[k].y==s)?1:0)+((v[k].z==s)?1:0)+((v[k].w==s)?1:0);
      lt  += ((v[k].x==s&&j0<e)?1:0)+((v[k].y==s&&j0+1<e)?1:0)+((v[k].z==s&&j0+2<e)?1:0)+((v[k].w==s&&j0+3<e)?1:0);
    }
  }
  rankA[e]=lt;
  if(lt==tot-1) cnt[s]=tot;
}

__global__ void csr_scan_kernel(const int* __restrict__ cnt, int* __restrict__ coff){
  __shared__ int s[NNODES];
  int tid=threadIdx.x;
  s[tid]=cnt[tid];
  __syncthreads();
  for(int d=1;d<NNODES;d<<=1){
    int v=(tid>=d)?s[tid-d]:0;
    __syncthreads();
    s[tid]+=v;
    __syncthreads();
  }
  coff[tid+1]=s[tid];
  if(tid==0) coff[0]=0;
}

__global__ void csr_scatter_kernel(const int* __restrict__ src, const int* __restrict__ coff,
    const int* __restrict__ rankA, int* __restrict__ list){
  int e=blockIdx.x*256+threadIdx.x;
  int s=src[e];
  list[coff[s]+rankA[e]]=e;
}

// ================= initial self-interaction =================
__global__ void si0_kernel(const float* __restrict__ feat, const float* __restrict__ w,
                           unsigned int* __restrict__ xh){
  __shared__ float s_f[64];
  __shared__ unsigned short s_v[128];
  int n=blockIdx.x, tid=threadIdx.x;
  if(tid<64) s_f[tid]=feat[n*64+tid];
  __syncthreads();
  float acc=0.f;
  for(int u=0;u<64;++u) acc += s_f[u]*w[u*128+tid];
  s_v[tid]=f2h(acc*0.125f);
  __syncthreads();
  if(tid<64) xh[(size_t)n*64+tid]=((unsigned int)s_v[2*tid+1]<<16)|s_v[2*tid];
}

// ================= merged-instruction fused conv =================
template<int MUL,int C,int EB,int NL,int USPLIT,int II>
__device__ __forceinline__ void instr_one(
  const unsigned int* __restrict__ W2h, int nW,
  const unsigned int (&hreg)[EB][6],
  const uint4* s_xp4, const float* s_B,
  float (&acc)[EB][9], int ubase, int uOff2, int w)
{
  constexpr int L1v = (NL==1)?0:IL1[II];
  constexpr int L3v = (NL==1)?((II<3)?II:0):IL3[II];
  constexpr int D1=2*L1v+1;
  constexpr int D3=2*L3v+1;
  constexpr int KOFF=IKOFF[L3v];
  constexpr int MULZ=MUL/USPLIT;
  constexpr int MZ2=MULZ/2;
  constexpr int UC=256/C;
  constexpr int CHZ=MUL/(UC*USPLIT);
  constexpr int CB=(L1v==0)?0:((L1v==1)?MZ2:4*MZ2);
  static_assert(EB==4,"EB must be 4");
  static_assert(CHZ>=2 && (CHZ&1)==0,"CHZ even");
  const unsigned int* Wp = W2h + (size_t)(II*MUL*C) + (size_t)ubase*C + w;
  const float* sB = s_B + II*EB*25;
  float a2[EB][D1];
  #pragma unroll
  for(int e=0;e<EB;++e){
    #pragma unroll
    for(int i=0;i<D1;++i) a2[e][i]=0.f;
  }
  #pragma unroll 2
  for(int u2=0;u2<CHZ/2;++u2){
    unsigned int wv0[6],wv1[6];
    #pragma unroll
    for(int r=0;r<6;++r){
      wv0[r]=Wp[(size_t)r*nW + (size_t)(2*u2)*C];
      wv1[r]=Wp[(size_t)r*nW + (size_t)(2*u2+1)*C];
    }
    unsigned int wi2[EB];
    #pragma unroll
    for(int e=0;e<EB;++e){
      float w0=0.f,w1=0.f;
      #pragma unroll
      for(int r=0;r<6;++r){ w0=dot2f(hreg[e][r],wv0[r],w0); w1=dot2f(hreg[e][r],wv1[r],w1); }
      wi2[e]=pk2(w0,w1);
    }
    #pragma unroll
    for(int i=0;i<D1;++i){
      uint4 xv = s_xp4[CB + i*MZ2 + uOff2 + u2];
      a2[0][i]=dot2f(wi2[0],xv.x,a2[0][i]);
      a2[1][i]=dot2f(wi2[1],xv.y,a2[1][i]);
      a2[2][i]=dot2f(wi2[2],xv.z,a2[2][i]);
      a2[3][i]=dot2f(wi2[3],xv.w,a2[3][i]);
    }
  }
  #pragma unroll
  for(int e=0;e<EB;++e){
    #pragma unroll
    for(int k=0;k<D3;++k){
      float s=0.f;
      #pragma unroll
      for(int i=0;i<D1;++i) s += a2[e][i]*sB[e*25+i*5+k];
      acc[e][KOFF+k]+=s;
    }
  }
}

template<int MUL,int C,int EB,int NL,int USPLIT>
__global__ __launch_bounds__(256,3) void conv_kernel(
  const unsigned int* __restrict__ xh, const unsigned int* __restrict__ W2h, int nW,
  const unsigned int* __restrict__ hb, const float* __restrict__ shb,
  const int* __restrict__ dstp, const float* __restrict__ w3j,
  unsigned int* __restrict__ msg0, unsigned int* __restrict__ msg1)
{
  constexpr int MUL2=MUL/2;
  constexpr int MULZ=MUL/USPLIT;
  constexpr int MZ2=MULZ/2;
  constexpr int ROW=(NL==1)?MUL2:9*MUL2;
  constexpr int SROW=(NL==1)?MZ2:9*MZ2;
  constexpr int UC=256/C;
  constexpr int CHZ=MUL/(UC*USPLIT);
  constexpr int NB=NEDGES/EB;
  constexpr int NI=(NL==1)?3:11;
  constexpr int SEG=9*C/2;                  // u32 per edge msg row
  __shared__ unsigned int s_xp[SROW*EB];
  __shared__ float s_B[NI*EB*25];
  __shared__ float s_red[9*256];
  __shared__ unsigned short s_msg[EB*9*C];
  int tid=threadIdx.x;
  int bid=blockIdx.x;
  int zz=bid/NB, et=bid-zz*NB;
  int e0=et*EB;
  unsigned int* msg=(zz==0)?msg0:msg1;
  // stage x (z-restricted, packed u-pairs, transposed over e)
  for(int ix=tid; ix<EB*SROW; ix+=256){
    int e=ix/SROW, c=ix-e*SROW;
    int l1,i,u2l;
    if(NL==1){ l1=0;i=0;u2l=c; }
    else{
      if(c<MZ2){l1=0;i=0;u2l=c;}
      else if(c<4*MZ2){int t=c-MZ2;i=t/MZ2;u2l=t-i*MZ2;l1=1;}
      else{int t=c-4*MZ2;i=t/MZ2;u2l=t-i*MZ2;l1=2;}
    }
    int gb=(l1==0)?0:((l1==1)?MUL2:4*MUL2);
    int dn=dstp[e0+e];
    s_xp[c*EB+e]=xh[(size_t)dn*ROW + gb + i*MUL2 + zz*MZ2 + u2l];
  }
  // B matrices for all NI instructions
  for(int ix=tid; ix<NI*EB*25; ix+=256){
    int ii=ix/(EB*25); int rem=ix%(EB*25); int e=rem/25; int q=rem%25;
    int i=q/5,k=q%5;
    int l1=(NL==1)?0:IL1[ii];
    int l2=(NL==1)?ii:IL2[ii];
    int l3=(NL==1)?ii:IL3[ii];
    int w3o=(NL==1)?((ii==0)?0:((ii==1)?1:10)):IW3O[ii];
    int d1=2*l1+1,d2=2*l2+1,d3v=2*l3+1;
    float v=0.f;
    if(i<d1&&k<d3v){
      for(int j=0;j<d2;++j) v+=shb[(size_t)(e0+e)*9+l2*l2+j]*w3j[w3o+(i*d2+j)*d3v+k];
      float fan=(NL==1)?(float)MUL:(float)(IFANM[l3]*MUL);
      v*=sqrtf((float)(2*l3+1)/fan);
    }
    s_B[(ii*EB+e)*25+q]=v;
  }
  __syncthreads();
  int w=tid%C, uc=tid/C;
  int ubase=zz*MULZ+uc*CHZ;
  int uOff2=uc*(CHZ/2);
  unsigned int hreg[EB][6];
  #pragma unroll
  for(int e=0;e<EB;++e){
    #pragma unroll
    for(int r=0;r<6;++r) hreg[e][r]=hb[(size_t)(e0+e)*6+r];
  }
  const uint4* s_xp4=(const uint4*)s_xp;
  float acc[EB][9];
  #pragma unroll
  for(int e=0;e<EB;++e){
    #pragma unroll
    for(int kk=0;kk<9;++kk) acc[e][kk]=0.f;
  }
  instr_one<MUL,C,EB,NL,USPLIT,0>(W2h,nW,hreg,s_xp4,s_B,acc,ubase,uOff2,w);
  instr_one<MUL,C,EB,NL,USPLIT,1>(W2h,nW,hreg,s_xp4,s_B,acc,ubase,uOff2,w);
  instr_one<MUL,C,EB,NL,USPLIT,2>(W2h,nW,hreg,s_xp4,s_B,acc,ubase,uOff2,w);
  if constexpr (NL==3){
    instr_one<MUL,C,EB,NL,USPLIT,3>(W2h,nW,hreg,s_xp4,s_B,acc,ubase,uOff2,w);
    instr_one<MUL,C,EB,NL,USPLIT,4>(W2h,nW,hreg,s_xp4,s_B,acc,ubase,uOff2,w);
    instr_one<MUL,C,EB,NL,USPLIT,5>(W2h,nW,hreg,s_xp4,s_B,acc,ubase,uOff2,w);
    instr_one<MUL,C,EB,NL,USPLIT,6>(W2h,nW,hreg,s_xp4,s_B,acc,ubase,uOff2,w);
    instr_one<MUL,C,EB,NL,USPLIT,7>(W2h,nW,hreg,s_xp4,s_B,acc,ubase,uOff2,w);
    instr_one<MUL,C,EB,NL,USPLIT,8>(W2h,nW,hreg,s_xp4,s_B,acc,ubase,uOff2,w);
    instr_one<MUL,C,EB,NL,USPLIT,9>(W2h,nW,hreg,s_xp4,s_B,acc,ubase,uOff2,w);
    instr_one<MUL,C,EB,NL,USPLIT,10>(W2h,nW,hreg,s_xp4,s_B,acc,ubase,uOff2,w);
  }
  // epilogue: reduce across uc groups, pack msg rows whole
  for(int e=0;e<EB;++e){
    #pragma unroll
    for(int kk=0;kk<9;++kk) s_red[kk*256+tid]=acc[e][kk];
    __syncthreads();
    for(int kk=uc;kk<9;kk+=UC){
      float s=0.f;
      #pragma unroll
      for(int c2=0;c2<UC;++c2) s+=s_red[kk*256+c2*C+w];
      int pos=(kk==0)? w : ((kk<4)? (C+w*3+(kk-1)) : (4*C+w*5+(kk-4)));
      s_msg[e*9*C+pos]=f2h(s);
    }
    __syncthreads();
  }
  const unsigned int* sm32=(const unsigned int*)s_msg;
  for(int ix=tid; ix<EB*SEG; ix+=256){
    int e=ix/SEG, o=ix-e*SEG;
    msg[(size_t)(e0+e)*SEG + o] = sm32[e*SEG+o];
  }
}

// ================= fused aggregate + pnorm + SI + nonlin -> packed f16 =================
template<int MUL>
__global__ void agg_post_kernel(const unsigned int* __restrict__ msg0,
                                const unsigned int* __restrict__ msg1,
                                const int* __restrict__ coff, const int* __restrict__ list,
                                const float* __restrict__ siw, const float* __restrict__ nlb,
                                unsigned int* __restrict__ xh){
  constexpr int W32=MUL*9/2;
  constexpr int ROW=9*MUL/2;
  __shared__ float s_in[MUL*9];
  __shared__ unsigned short s_out[MUL*9];
  __shared__ float red[256];
  int n=blockIdx.x, tid=threadIdx.x;
  int b=coff[n], en=coff[n+1];
  float ss=0.f;
  for(int c32=tid;c32<W32;c32+=256){
    float a0=0.f,a1=0.f;
    for(int j=b;j<en;++j){
      size_t o=(size_t)list[j]*W32+c32;
      half2v p=u2h2(msg0[o]); a0+=(float)p.x; a1+=(float)p.y;
      if(msg1){ half2v q=u2h2(msg1[o]); a0+=(float)q.x; a1+=(float)q.y; }
    }
    s_in[2*c32]=a0; s_in[2*c32+1]=a1;
    ss+=a0*a0+a1*a1;
  }
  red[tid]=ss; __syncthreads();
  for(int d=128;d>0;d>>=1){ if(tid<d) red[tid]+=red[tid+d]; __syncthreads(); }
  float scale=1.f/(sqrtf(red[0])+1e-6f);
  const float inv=scale/sqrtf((float)MUL);
  float b0=nlb[0], b1=nlb[1], b2=nlb[2];
  for(int p=tid;p<3*MUL;p+=256){
    int l=p/MUL, wo=p%MUL;
    if(l==0){
      const float* Wl=siw;
      float a=0.f;
      for(int u=0;u<MUL;++u) a+=s_in[u]*Wl[(size_t)u*MUL+wo];
      s_out[wo]=f2h(softplusf(a*inv+b0));
    } else if(l==1){
      const float* Wl=siw+(size_t)MUL*MUL;
      float v0=0.f,v1=0.f,v2=0.f;
      for(int u=0;u<MUL;++u){
        float wv=Wl[(size_t)u*MUL+wo];
        int bi=MUL+u*3;
        v0+=s_in[bi]*wv; v1+=s_in[bi+1]*wv; v2+=s_in[bi+2]*wv;
      }
      v0*=inv; v1*=inv; v2*=inv;
      float gate=softplusf(sqrtf(v0*v0+v1*v1+v2*v2+1e-24f)+b1);
      int ob=MUL+wo*3;
      s_out[ob]=f2h(v0*gate); s_out[ob+1]=f2h(v1*gate); s_out[ob+2]=f2h(v2*gate);
    } else {
      const float* Wl=siw+(size_t)2*MUL*MUL;
      float v0=0.f,v1=0.f,v2=0.f,v3=0.f,v4=0.f;
      for(int u=0;u<MUL;++u){
        float wv=Wl[(size_t)u*MUL+wo];
        int bi=4*MUL+u*5;
        v0+=s_in[bi]*wv; v1+=s_in[bi+1]*wv; v2+=s_in[bi+2]*wv; v3+=s_in[bi+3]*wv; v4+=s_in[bi+4]*wv;
      }
      v0*=inv; v1*=inv; v2*=inv; v3*=inv; v4*=inv;
      float gate=softplusf(sqrtf(v0*v0+v1*v1+v2*v2+v3*v3+v4*v4+1e-24f)+b2);
      int ob=4*MUL+wo*5;
      s_out[ob]=f2h(v0*gate); s_out[ob+1]=f2h(v1*gate); s_out[ob+2]=f2h(v2*gate);
      s_out[ob+3]=f2h(v3*gate); s_out[ob+4]=f2h(v4*gate);
    }
  }
  __syncthreads();
  for(int p=tid;p<ROW;p+=256){
    int l,i,u2;
    if(p<MUL/2){l=0;i=0;u2=p;}
    else if(p<2*MUL){int t=p-MUL/2;i=t/(MUL/2);u2=t%(MUL/2);l=1;}
    else{int t=p-2*MUL;i=t/(MUL/2);u2=t%(MUL/2);l=2;}
    int d=2*l+1, sb=MUL*l*l;
    unsigned short a=s_out[sb+(2*u2)*d+i], bb=s_out[sb+(2*u2+1)*d+i];
    xh[(size_t)n*ROW+p]=((unsigned int)bb<<16)|a;
  }
}

// ================= final l=0 self interaction =================
__global__ void final_kernel(const unsigned int* __restrict__ xh, const float* __restrict__ fsi,
                             float* __restrict__ out){
  int gid=blockIdx.x*blockDim.x+threadIdx.x;
  if(gid>=NNODES*32) return;
  int n=gid/32, wo=gid%32;
  float s=0.f;
  for(int u2=0;u2<16;++u2){
    half2v p=u2h2(xh[(size_t)n*144+u2]);
    s += (float)p.x*fsi[(2*u2)*32+wo] + (float)p.y*fsi[(2*u2+1)*32+wo];
  }
  out[gid]=s*(1.f/sqrtf(32.f));
}

// ================= host =================
extern "C" void kernel_launch(void* const* d_in, const int* in_sizes, int n_in,
                              void* d_out, int out_size, void* d_ws, size_t ws_size,
                              hipStream_t stream) {
  const float* pos    = (const float*)d_in[0];
  const float* feat   = (const float*)d_in[1];
  const int*   ei     = (const int*)d_in[2];
  const float* si0w   = (const float*)d_in[3];
  const float* c1_rw1 = (const float*)d_in[4];
  const float* c1_rw2 = (const float*)d_in[5];
  const float* si1w   = (const float*)d_in[6];
  const float* nl1b   = (const float*)d_in[7];
  const float* c2_rw1 = (const float*)d_in[8];
  const float* c2_rw2 = (const float*)d_in[9];
  const float* si2w   = (const float*)d_in[10];
  const float* nl2b   = (const float*)d_in[11];
  const float* c3_rw1 = (const float*)d_in[12];
  const float* c3_rw2 = (const float*)d_in[13];
  const float* si3w   = (const float*)d_in[14];
  const float* nl3b   = (const float*)d_in[15];
  const float* fsiw   = (const float*)d_in[16];

  float* ws_f=(float*)d_ws;
  float* w3   = ws_f+OFF_W3J;
  float* sh   = ws_f+OFF_SH;
  unsigned int* h1   = (unsigned int*)(ws_f+OFF_H1);
  unsigned int* h2   = (unsigned int*)(ws_f+OFF_H2);
  unsigned int* h3   = (unsigned int*)(ws_f+OFF_H3);
  unsigned int* w2p1 = (unsigned int*)(ws_f+OFF_W2P1);
  unsigned int* w2p2 = (unsigned int*)(ws_f+OFF_W2P2);
  unsigned int* w2p3 = (unsigned int*)(ws_f+OFF_W2P3);
  unsigned int* xh   = (unsigned int*)(ws_f+OFF_XH);
  unsigned int* msgA = (unsigned int*)(ws_f+OFF_MSGA);
  unsigned int* msgB = (unsigned int*)(ws_f+OFF_MSGB);
  unsigned int* V    = msgB;
  int* cnt    = (int*)(ws_f+OFF_CNT);
  int* coff   = (int*)(ws_f+OFF_COFF);
  int* clist  = (int*)(ws_f+OFF_LIST);
  int* rankA  = (int*)(ws_f+OFF_RANK);
  const int* src  = ei;
  const int* dstp = ei+NEDGES;

  const bool split = ws_size >= WS_NEED_SPLIT;
  const int NB = NEDGES/4;

  w3j_kernel<<<dim3(11),dim3(128),0,stream>>>(w3);
  edge_prep_kernel<<<dim3(NEDGES/256),dim3(256),0,stream>>>(pos,ei,c1_rw1,c2_rw1,c3_rw1, sh,h1,h2,h3);
  if(split){
    w1pack_kernel<<<dim3((384*768+255)/256),dim3(256),0,stream>>>(c1_rw2,w2p1);
  } else {
    w2pack_kernel<<<dim3((6*49152+255)/256),dim3(256),0,stream>>>(c1_rw2,w2p1,49152);
  }
  w2pack_kernel<<<dim3((6*90112+255)/256),dim3(256),0,stream>>>(c2_rw2,w2p2,90112);
  w2pack_kernel<<<dim3((6*22528+255)/256),dim3(256),0,stream>>>(c3_rw2,w2p3,22528);

  hipMemsetAsync(cnt,0,NNODES*sizeof(int),stream);
  csr_rank_kernel<<<dim3(NEDGES/256),dim3(256),0,stream>>>(src,cnt,rankA);
  csr_scan_kernel<<<dim3(1),dim3(NNODES),0,stream>>>(cnt,coff);
  csr_scatter_kernel<<<dim3(NEDGES/256),dim3(256),0,stream>>>(src,coff,rankA,clist);

  si0_kernel<<<dim3(NNODES),dim3(128),0,stream>>>(feat,si0w,xh);

  if(split){
    // layer 1: node-side GEMM + light edge pass
    vgemm1_kernel<<<dim3(NNODES/4),dim3(384),0,stream>>>(xh,w2p1,V);
    conv1_edge_kernel<<<dim3(NEDGES/2),dim3(384),0,stream>>>(V,h1,sh,dstp,w3,msgA);
    agg_post_kernel<128><<<dim3(NNODES),dim3(256),0,stream>>>(msgA,(const unsigned int*)nullptr,coff,clist,si1w,nl1b,xh);
    // layer 2: merged 11-instruction conv, z-split over msgA/msgB
    conv_kernel<128,64,4,3,2><<<dim3(NB*2),dim3(256),0,stream>>>(xh,w2p2,90112,h2,sh,dstp,w3,msgA,msgB);
    agg_post_kernel<64><<<dim3(NNODES),dim3(256),0,stream>>>(msgA,msgB,coff,clist,si2w,nl2b,xh);
    // layer 3: merged, single z
    conv_kernel<64,32,4,3,1><<<dim3(NB),dim3(256),0,stream>>>(xh,w2p3,22528,h3,sh,dstp,w3,msgA,msgA);
    agg_post_kernel<32><<<dim3(NNODES),dim3(256),0,stream>>>(msgA,(const unsigned int*)nullptr,coff,clist,si3w,nl3b,xh);
  } else {
    conv_kernel<128,128,4,1,1><<<dim3(NB),dim3(256),0,stream>>>(xh,w2p1,49152,h1,sh,dstp,w3,msgA,msgA);
    agg_post_kernel<128><<<dim3(NNODES),dim3(256),0,stream>>>(msgA,(const unsigned int*)nullptr,coff,clist,si1w,nl1b,xh);
    conv_kernel<128,64,4,3,1><<<dim3(NB),dim3(256),0,stream>>>(xh,w2p2,90112,h2,sh,dstp,w3,msgA,msgA);
    agg_post_kernel<64><<<dim3(NNODES),dim3(256),0,stream>>>(msgA,(const unsigned int*)nullptr,coff,clist,si2w,nl2b,xh);
    conv_kernel<64,32,4,3,1><<<dim3(NB),dim3(256),0,stream>>>(xh,w2p3,22528,h3,sh,dstp,w3,msgA,msgA);
    agg_post_kernel<32><<<dim3(NNODES),dim3(256),0,stream>>>(msgA,(const unsigned int*)nullptr,coff,clist,si3w,nl3b,xh);
  }

  final_kernel<<<dim3((NNODES*32+255)/256),dim3(256),0,stream>>>(xh,fsiw,(float*)d_out);
}

// Round 11
// 322.639 us; speedup vs baseline: 1.8693x; 1.8693x over previous
//
#include <hip/hip_runtime.h>
#include <cmath>
#include <cstdint>

#define NNODES 512
#define NEDGES 2048

typedef _Float16 half2v __attribute__((ext_vector_type(2)));

// ---- workspace layout (float offsets) ----
#define OFF_W3J   0
#define OFF_SH    512
#define OFF_H1    (OFF_SH + NEDGES*9)
#define OFF_H2    (OFF_H1 + NEDGES*6)
#define OFF_H3    (OFF_H2 + NEDGES*6)
#define OFF_W2P1  (OFF_H3 + NEDGES*6)           // split: W1p (384*768); !split: r-major pack
#define OFF_W2P2  (OFF_W2P1 + 6*49152)
#define OFF_W2P3  (OFF_W2P2 + 6*90112)
#define OFF_XH    (OFF_W2P3 + 6*22528)
#define OFF_XB    (OFF_XH + NNODES*576)
#define OFF_MSGA  (OFF_XB + NNODES*1152)
#define OFF_CNT   (OFF_MSGA + NEDGES*576)
#define OFF_COFF  (OFF_CNT + 512)
#define OFF_LIST  (OFF_COFF + 1024)
#define OFF_RANK  (OFF_LIST + 2048)
#define OFF_MSGB  (OFF_RANK + 2048)             // split: also V
#define WS_NEED_SPLIT ((size_t)(OFF_MSGB + NEDGES*576) * 4)

// ---------- helpers ----------
__device__ __forceinline__ unsigned int packh2f(float a, float b){
  half2v h; h.x=(_Float16)a; h.y=(_Float16)b;
  return __builtin_bit_cast(unsigned int, h);
}
__device__ __forceinline__ half2v u2h2(unsigned int u){ return __builtin_bit_cast(half2v, u); }
__device__ __forceinline__ float dot2f(unsigned int a, unsigned int b, float c){
#if __has_builtin(__builtin_amdgcn_fdot2)
  return __builtin_amdgcn_fdot2(u2h2(a), u2h2(b), c, false);
#else
  half2v ha=u2h2(a), hb=u2h2(b);
  return c + (float)ha.x*(float)hb.x + (float)ha.y*(float)hb.y;
#endif
}
__device__ __forceinline__ unsigned int pk2(float a, float b){
#if __has_builtin(__builtin_amdgcn_cvt_pkrtz)
  auto h=__builtin_amdgcn_cvt_pkrtz(a,b);
  return __builtin_bit_cast(unsigned int,h);
#else
  return packh2f(a,b);
#endif
}
__device__ __forceinline__ unsigned short f2h(float f){
  _Float16 h=(_Float16)f; return __builtin_bit_cast(unsigned short,h);
}
__device__ __forceinline__ float softplusf(float v){ return fmaxf(v,0.f)+log1pf(expf(-fabsf(v))); }

// ================= W3J (fp64, on device) =================
__device__ double dfact(int n){ double f=1.0; for(int i=2;i<=n;++i) f*=(double)i; return f; }

__device__ double w3j_c_dev(int l1,int l2,int l3,int m1,int m2,int m3){
  if (m1+m2+m3 != 0) return 0.0;
  int p = l1 - l2 - m3;
  double sign = (((p%2)+2)%2) ? -1.0 : 1.0;
  double pref = sign*sqrt(dfact(l1+l2-l3)*dfact(l1-l2+l3)*dfact(-l1+l2+l3)/dfact(l1+l2+l3+1)
              *dfact(l1+m1)*dfact(l1-m1)*dfact(l2+m2)*dfact(l2-m2)*dfact(l3+m3)*dfact(l3-m3));
  double s=0.0;
  for (int t=0;t<=l1+l2-l3;++t){
    int d0=t, d1v=l3-l2+t+m1, d2v=l3-l1+t-m2, d3v=l1+l2-l3-t, d4=l1-t-m1, d5=l2-t+m2;
    if (d0<0||d1v<0||d2v<0||d3v<0||d4<0||d5<0) continue;
    double den=dfact(d0)*dfact(d1v)*dfact(d2v)*dfact(d3v)*dfact(d4)*dfact(d5);
    s += ((t&1)?-1.0:1.0)/den;
  }
  return pref*s;
}

__device__ void u_real_dev(int l, double Ur[5][5], double Ui[5][5]){
  for(int a=0;a<5;++a)for(int b=0;b<5;++b){Ur[a][b]=0.0;Ui[a][b]=0.0;}
  Ur[l][l]=1.0;
  double inv2 = 1.0/sqrt(2.0);
  for(int m=1;m<=l;++m){
    double sgn = (m&1)?-1.0:1.0;
    Ur[l+m][l+m] = sgn*inv2;
    Ur[l+m][l-m] = inv2;
    Ui[l-m][l-m] = inv2;
    Ui[l-m][l+m] = -sgn*inv2;
  }
}

__global__ void w3j_kernel(float* __restrict__ out){
  const int L1[11]={0,0,0,1,1,1,1,2,2,2,2};
  const int L2[11]={0,1,2,0,1,1,2,0,1,2,2};
  const int L3[11]={0,1,2,1,0,2,1,2,1,0,2};
  const int OFF[11]={0,1,10,35,44,53,98,143,168,213,238};
  int t = blockIdx.x;
  int tid = threadIdx.x;
  int l1=L1[t], l2=L2[t], l3=L3[t];
  int d1=2*l1+1, d2=2*l2+1, d3=2*l3+1;
  int sz=d1*d2*d3;
  __shared__ double Wt[125];
  __shared__ double U1r[5][5],U1i[5][5],U2r[5][5],U2i[5][5],U3r[5][5],U3i[5][5];
  __shared__ double Cv[125];
  __shared__ double red[128];
  for(int idx=tid; idx<sz; idx+=128){
    int a=idx/(d2*d3), rem=idx%(d2*d3), b=rem/d3, c=rem%d3;
    Wt[idx]=w3j_c_dev(l1,l2,l3,a-l1,b-l2,c-l3);
  }
  if(tid==0) u_real_dev(l1,U1r,U1i);
  if(tid==1) u_real_dev(l2,U2r,U2i);
  if(tid==2) u_real_dev(l3,U3r,U3i);
  __syncthreads();
  for(int idx=tid; idx<sz; idx+=128){
    int a=idx/(d2*d3), rem=idx%(d2*d3), b=rem/d3, c=rem%d3;
    double cr=0.0, ci=0.0;
    for(int m=0;m<d1;++m)for(int n=0;n<d2;++n){
      double t2r = U1r[a][m]*U2r[b][n]-U1i[a][m]*U2i[b][n];
      double t2i = U1r[a][m]*U2i[b][n]+U1i[a][m]*U2r[b][n];
      if (t2r==0.0 && t2i==0.0) continue;
      for(int o=0;o<d3;++o){
        double wv=Wt[(m*d2+n)*d3+o];
        if (wv==0.0) continue;
        double t3r=t2r*U3r[c][o]-t2i*U3i[c][o];
        double t3i=t2r*U3i[c][o]+t2i*U3r[c][o];
        cr += t3r*wv; ci += t3i*wv;
      }
    }
    Cv[idx]=cr+ci;
  }
  __syncthreads();
  double s=0.0;
  for(int idx=tid; idx<sz; idx+=128) s+=Cv[idx]*Cv[idx];
  red[tid]=s; __syncthreads();
  for(int d=64; d>0; d>>=1){ if(tid<d) red[tid]+=red[tid+d]; __syncthreads(); }
  double nrm = sqrt(red[0]);
  double inv = (nrm>0.0)?1.0/nrm:0.0;
  for(int idx=tid; idx<sz; idx+=128) out[OFF[t]+idx]=(float)(Cv[idx]*inv);
}

// ================= Edge prep =================
__global__ void edge_prep_kernel(const float* __restrict__ pos, const int* __restrict__ ei,
    const float* __restrict__ rw1a, const float* __restrict__ rw1b, const float* __restrict__ rw1c,
    float* __restrict__ sh, unsigned int* __restrict__ h1, unsigned int* __restrict__ h2,
    unsigned int* __restrict__ h3){
  int e = blockIdx.x*blockDim.x+threadIdx.x;
  if (e>=NEDGES) return;
  int s = ei[e], d = ei[NEDGES+e];
  float vx=pos[3*s]-pos[3*d], vy=pos[3*s+1]-pos[3*d+1], vz=pos[3*s+2]-pos[3*d+2];
  float dist=sqrtf(vx*vx+vy*vy+vz*vz);
  float dm = fmaxf(dist,1e-12f);
  float x=vx/dm, y=vy/dm, z=vz/dm;
  const float s3=sqrtf(3.f), s15=sqrtf(15.f), s5=sqrtf(5.f);
  float shv[9];
  shv[0]=1.f; shv[1]=s3*y; shv[2]=s3*z; shv[3]=s3*x;
  shv[4]=s15*x*y; shv[5]=s15*y*z; shv[6]=0.5f*s5*(3.f*z*z-1.f); shv[7]=s15*x*z; shv[8]=0.5f*s15*(x*x-y*y);
  #pragma unroll
  for(int i=0;i<9;++i) sh[e*9+i]=shv[i];
  float rb[11];
  #pragma unroll
  for(int i=0;i<11;++i){ float diff=(dist-0.8f*(float)i)*(1.f/0.8f); rb[i]=expf(-diff*diff)*(1.f/1.12f); }
  const float c1 = 1.f/sqrtf(11.f);
  const float c2 = sqrtf(2.f)/sqrtf(12.f);
  const float* rws[3]={rw1a,rw1b,rw1c};
  unsigned int* outs[3]={h1,h2,h3};
  for(int L=0;L<3;++L){
    float hv[12];
    #pragma unroll
    for(int r=0;r<12;++r){
      float t=0.f;
      #pragma unroll
      for(int k=0;k<11;++k) t+=rb[k]*rws[L][k*12+r];
      t*=c1;
      hv[r]=fmaxf(t,0.f)*c2;
    }
    #pragma unroll
    for(int r2=0;r2<6;++r2) outs[L][e*6+r2]=packh2f(hv[2*r2],hv[2*r2+1]);
  }
}

// ================= W2 fp32 -> packed f16 pairs over r (r-major, proven) =================
__global__ void w2pack_kernel(const float* __restrict__ w2, unsigned int* __restrict__ out, int nW){
  int idx=blockIdx.x*256+threadIdx.x;
  if(idx>=6*nW) return;
  int r2=idx/nW, c=idx-r2*nW;
  out[idx]=packh2f(w2[(size_t)(2*r2)*nW+c], w2[(size_t)(2*r2+1)*nW+c]);
}

// ===== layer-1 W pack (split path, node-side GEMM) =====
__global__ void w1pack_kernel(const float* __restrict__ w2, unsigned int* __restrict__ out){
  int idx=blockIdx.x*256+threadIdx.x;
  if(idx>=384*768) return;
  int col=idx/768, rem=idx-col*768;
  int r=rem/64, u2=rem-r*64;
  int i=col>>7, w=col&127;
  size_t s0=(size_t)r*49152 + i*16384 + (2*u2)*128 + w;
  out[idx]=packh2f(w2[s0], w2[s0+128]);
}

// ===== layer-1 node-side GEMM =====
__global__ __launch_bounds__(384) void vgemm1_kernel(const unsigned int* __restrict__ xh,
    const unsigned int* __restrict__ w1p, unsigned int* __restrict__ V){
  __shared__ __align__(16) unsigned int s_x[4][64];
  int tid=threadIdx.x;
  int n0=blockIdx.x*4;
  for(int ix=tid; ix<256; ix+=384){ int n=ix>>6, u2=ix&63; s_x[n][u2]=xh[(size_t)(n0+n)*64+u2]; }
  __syncthreads();
  int col=tid;
  float acc[4][12];
  #pragma unroll
  for(int n=0;n<4;++n)
    #pragma unroll
    for(int r=0;r<12;++r) acc[n][r]=0.f;
  const uint4* Wp=(const uint4*)(w1p + (size_t)col*768);
  for(int u4=0;u4<16;++u4){
    uint4 xv[4];
    #pragma unroll
    for(int n=0;n<4;++n) xv[n]=((const uint4*)s_x[n])[u4];
    #pragma unroll
    for(int r=0;r<12;++r){
      uint4 wv=Wp[r*16+u4];
      #pragma unroll
      for(int n=0;n<4;++n){
        acc[n][r]=dot2f(xv[n].x,wv.x,acc[n][r]);
        acc[n][r]=dot2f(xv[n].y,wv.y,acc[n][r]);
        acc[n][r]=dot2f(xv[n].z,wv.z,acc[n][r]);
        acc[n][r]=dot2f(xv[n].w,wv.w,acc[n][r]);
      }
    }
  }
  #pragma unroll
  for(int n=0;n<4;++n)
    #pragma unroll
    for(int r2=0;r2<6;++r2)
      V[((size_t)(n0+n)*384+col)*6+r2]=pk2(acc[n][2*r2],acc[n][2*r2+1]);
}

// ===== layer-1 edge pass =====
__global__ __launch_bounds__(384) void conv1_edge_kernel(const unsigned int* __restrict__ V,
    const unsigned int* __restrict__ h1, const float* __restrict__ shb,
    const int* __restrict__ dstp, const float* __restrict__ w3j,
    unsigned int* __restrict__ msgA){
  const int W3O[3]={0,1,10};
  unsigned short* m16=(unsigned short*)msgA;
  int tid=threadIdx.x;
  int col=tid;
  int i=col>>7, w=col&127;
  int d3=2*i+1;
  float alpha=sqrtf((float)(2*i+1))*(1.f/sqrtf(128.f));
  int e0=blockIdx.x*2;
  #pragma unroll
  for(int s=0;s<2;++s){
    int e=e0+s;
    int n=dstp[e];
    const unsigned int* vp=V+((size_t)n*384+col)*6;
    float G=0.f;
    #pragma unroll
    for(int r2=0;r2<6;++r2) G=dot2f(h1[(size_t)e*6+r2], vp[r2], G);
    int base=(i==0)?0:((i==1)?128:512);
    for(int k=0;k<d3;++k){
      float B=0.f;
      for(int j=0;j<d3;++j) B += shb[(size_t)e*9+i*i+j]*w3j[W3O[i]+j*d3+k];
      m16[(size_t)e*1152 + base + w*d3 + k]=f2h(G*B*alpha);
    }
  }
}

// ================= CSR build: rank -> scan -> scatter =================
__global__ __launch_bounds__(256) void csr_rank_kernel(const int* __restrict__ src,
    int* __restrict__ cnt, int* __restrict__ rankA){
  __shared__ int s_src[NEDGES];
  int tid=threadIdx.x;
  int4* s4=(int4*)s_src;
  const int4* g4=(const int4*)src;
  for(int i=tid;i<NEDGES/4;i+=256) s4[i]=g4[i];
  __syncthreads();
  int e=blockIdx.x*256+tid;
  int s=s_src[e];
  int lt=0, tot=0;
  for(int b=0;b<NEDGES/4;b+=8){
    int4 v[8];
    #pragma unroll
    for(int k=0;k<8;++k) v[k]=s4[b+k];
    #pragma unroll
    for(int k=0;k<8;++k){
      int j0=4*(b+k);
      tot += ((v[k].x==s)?1:0)+((v[k].y==s)?1:0)+((v[k].z==s)?1:0)+((v[k].w==s)?1:0);
      lt  += ((v[k].x==s&&j0<e)?1:0)+((v[k].y==s&&j0+1<e)?1:0)+((v[k].z==s&&j0+2<e)?1:0)+((v[k].w==s&&j0+3<e)?1:0);
    }
  }
  rankA[e]=lt;
  if(lt==tot-1) cnt[s]=tot;
}

__global__ void csr_scan_kernel(const int* __restrict__ cnt, int* __restrict__ coff){
  __shared__ int s[NNODES];
  int tid=threadIdx.x;
  s[tid]=cnt[tid];
  __syncthreads();
  for(int d=1;d<NNODES;d<<=1){
    int v=(tid>=d)?s[tid-d]:0;
    __syncthreads();
    s[tid]+=v;
    __syncthreads();
  }
  coff[tid+1]=s[tid];
  if(tid==0) coff[0]=0;
}

__global__ void csr_scatter_kernel(const int* __restrict__ src, const int* __restrict__ coff,
    const int* __restrict__ rankA, int* __restrict__ list){
  int e=blockIdx.x*256+threadIdx.x;
  int s=src[e];
  list[coff[s]+rankA[e]]=e;
}

// ================= initial self-interaction =================
__global__ void si0_kernel(const float* __restrict__ feat, const float* __restrict__ w,
                           unsigned int* __restrict__ xh){
  __shared__ float s_f[64];
  __shared__ unsigned short s_v[128];
  int n=blockIdx.x, tid=threadIdx.x;
  if(tid<64) s_f[tid]=feat[n*64+tid];
  __syncthreads();
  float acc=0.f;
  for(int u=0;u<64;++u) acc += s_f[u]*w[u*128+tid];
  s_v[tid]=f2h(acc*0.125f);
  __syncthreads();
  if(tid<64) xh[(size_t)n*64+tid]=((unsigned int)s_v[2*tid+1]<<16)|s_v[2*tid];
}

// ================= fused conv (R7 proven structure) =================
struct CInstr { int l1,l2,l3,woff,w3off; float alpha; };
struct LayerArg { CInstr ins[3][4]; int cnt[3]; int gOf[8]; int rank[8]; int nxg[3]; };

template<int MUL,int C,int EB,int NL,int USPLIT,int D3,int L1v>
__device__ __forceinline__ void instr_body(
  const unsigned int* __restrict__ W2h, int nW, int woff,
  const unsigned int (&hreg)[EB][6],
  const uint4* s_xp4, const float* sB,
  float (&acc)[EB][D3], int ubase, int uOff2, int w)
{
  constexpr int D1=2*L1v+1;
  constexpr int MULZ=MUL/USPLIT;
  constexpr int MZ2=MULZ/2;
  constexpr int UC=256/C;
  constexpr int CHZ=MUL/(UC*USPLIT);
  constexpr int CB=(L1v==0)?0:((L1v==1)?MZ2:4*MZ2);
  static_assert(EB==4,"EB must be 4");
  static_assert(CHZ>=2 && (CHZ&1)==0,"CHZ even");
  const unsigned int* Wp = W2h + (size_t)woff + (size_t)ubase*C + w;
  float a2[EB][D1];
  #pragma unroll
  for(int e=0;e<EB;++e){
    #pragma unroll
    for(int i=0;i<D1;++i) a2[e][i]=0.f;
  }
  #pragma unroll 2
  for(int u2=0;u2<CHZ/2;++u2){
    unsigned int wv0[6],wv1[6];
    #pragma unroll
    for(int r=0;r<6;++r){
      wv0[r]=Wp[(size_t)r*nW + (size_t)(2*u2)*C];
      wv1[r]=Wp[(size_t)r*nW + (size_t)(2*u2+1)*C];
    }
    unsigned int wi2[EB];
    #pragma unroll
    for(int e=0;e<EB;++e){
      float w0=0.f,w1=0.f;
      #pragma unroll
      for(int r=0;r<6;++r){ w0=dot2f(hreg[e][r],wv0[r],w0); w1=dot2f(hreg[e][r],wv1[r],w1); }
      wi2[e]=pk2(w0,w1);
    }
    #pragma unroll
    for(int i=0;i<D1;++i){
      uint4 xv = s_xp4[CB + i*MZ2 + uOff2 + u2];
      a2[0][i]=dot2f(wi2[0],xv.x,a2[0][i]);
      a2[1][i]=dot2f(wi2[1],xv.y,a2[1][i]);
      a2[2][i]=dot2f(wi2[2],xv.z,a2[2][i]);
      a2[3][i]=dot2f(wi2[3],xv.w,a2[3][i]);
    }
  }
  #pragma unroll
  for(int e=0;e<EB;++e){
    #pragma unroll
    for(int k=0;k<D3;++k){
      float s=0.f;
      #pragma unroll
      for(int i=0;i<D1;++i) s += a2[e][i]*sB[e*25+i*5+k];
      acc[e][k]+=s;
    }
  }
}

template<int MUL,int C,int EB,int NL,int USPLIT,int D3,int NINS>
__device__ __forceinline__ void conv_main(
  const unsigned int* __restrict__ W2h, int nW,
  const unsigned int (&hreg)[EB][6],
  const uint4* s_xp4, const float* s_B, float* s_red, unsigned short* s_msg,
  unsigned int* __restrict__ msg, const LayerArg& la, int g, int e0,
  int w, int uc, int ubase, int uOff2)
{
  constexpr int UC=256/C;
  const int tid=threadIdx.x;
  float acc[EB][D3];
  #pragma unroll
  for(int e=0;e<EB;++e){
    #pragma unroll
    for(int k=0;k<D3;++k) acc[e][k]=0.f;
  }
  #pragma unroll
  for(int ii=0;ii<NINS;++ii){
    const int l1v=la.ins[g][ii].l1;
    const int woff=la.ins[g][ii].woff;
    switch(l1v){
      case 0: instr_body<MUL,C,EB,NL,USPLIT,D3,0>(W2h,nW,woff,hreg,s_xp4,s_B+ii*EB*25,acc,ubase,uOff2,w); break;
      case 1: instr_body<MUL,C,EB,NL,USPLIT,D3,1>(W2h,nW,woff,hreg,s_xp4,s_B+ii*EB*25,acc,ubase,uOff2,w); break;
      default: instr_body<MUL,C,EB,NL,USPLIT,D3,2>(W2h,nW,woff,hreg,s_xp4,s_B+ii*EB*25,acc,ubase,uOff2,w); break;
    }
  }
  constexpr int L3v=(D3-1)/2;
  constexpr int base32=(L3v==0)?0:((L3v==1)?C/2:2*C);
  constexpr int seg32=C*D3/2;
  for(int e=0;e<EB;++e){
    #pragma unroll
    for(int k=0;k<D3;++k) s_red[k*256+tid]=acc[e][k];
    __syncthreads();
    if(uc==0){
      #pragma unroll
      for(int k=0;k<D3;++k){
        float s=0.f;
        #pragma unroll
        for(int c2=0;c2<UC;++c2) s+=s_red[k*256+c2*C+w];
        s_msg[(e*C+w)*D3+k]=f2h(s);
      }
    }
    __syncthreads();
  }
  const unsigned int* sm32=(const unsigned int*)s_msg;
  for(int ix=tid; ix<EB*seg32; ix+=256){
    int e=ix/seg32, o=ix-e*seg32;
    msg[(size_t)(e0+e)*(9*C/2) + base32 + o] = sm32[e*seg32+o];
  }
}

template<int MUL,int C,int EB,int NL,int USPLIT>
__global__ __launch_bounds__(256,4) void conv_kernel(
  const unsigned int* __restrict__ xh, const unsigned int* __restrict__ W2h, int nW,
  const unsigned int* __restrict__ hb, const float* __restrict__ shb,
  const int* __restrict__ dstp, const float* __restrict__ w3j,
  unsigned int* __restrict__ msg0, unsigned int* __restrict__ msg1, LayerArg la)
{
  constexpr int MUL2=MUL/2;
  constexpr int MULZ=MUL/USPLIT;
  constexpr int MZ2=MULZ/2;
  constexpr int ROW=(NL==1)?MUL2:9*MUL2;
  constexpr int SROW=(NL==1)?MZ2:9*MZ2;
  constexpr int UC=256/C;
  constexpr int CHZ=MUL/(UC*USPLIT);
  constexpr int NB=NEDGES/EB;
  __shared__ unsigned int s_xp[SROW*EB];
  __shared__ float s_B[4*EB*25];
  __shared__ float s_red[5*256];
  __shared__ unsigned short s_msg[EB*C*5];
  int tid=threadIdx.x;
  int bid=blockIdx.x;
  int xcd=bid&7, slot=bid>>3;
  int g=la.gOf[xcd];
  int idx=slot*la.nxg[g]+la.rank[xcd];
  if(idx>=NB*USPLIT) return;
  int zz=idx/NB, et=idx-zz*NB;
  int e0=et*EB;
  unsigned int* msg=(zz==0)?msg0:msg1;
  for(int ix=tid; ix<EB*SROW; ix+=256){
    int e=ix/SROW, c=ix-(ix/SROW)*SROW;
    int l1,i,u2l;
    if(NL==1){ l1=0;i=0;u2l=c; }
    else{
      if(c<MZ2){l1=0;i=0;u2l=c;}
      else if(c<4*MZ2){int t=c-MZ2;i=t/MZ2;u2l=t-i*MZ2;l1=1;}
      else{int t=c-4*MZ2;i=t/MZ2;u2l=t-i*MZ2;l1=2;}
    }
    int gb=(l1==0)?0:((l1==1)?MUL2:4*MUL2);
    int dn=dstp[e0+e];
    s_xp[c*EB+e]=xh[(size_t)dn*ROW + gb + i*MUL2 + zz*MZ2 + u2l];
  }
  int nIns=la.cnt[g];
  for(int ix=tid; ix<nIns*EB*25; ix+=256){
    int ii=ix/(EB*25); int rem=ix%(EB*25); int e=rem/25; int q=rem%25;
    int i=q/5,k=q%5;
    CInstr I=la.ins[g][ii];
    int d1=2*I.l1+1,d2=2*I.l2+1,d3v=2*I.l3+1;
    float v=0.f;
    if(i<d1&&k<d3v){
      int sho=I.l2*I.l2;
      for(int j=0;j<d2;++j) v+=shb[(size_t)(e0+e)*9+sho+j]*w3j[I.w3off+(i*d2+j)*d3v+k];
      v*=I.alpha;
    }
    s_B[(ii*EB+e)*25+q]=v;
  }
  __syncthreads();
  int w=tid%C, uc=tid/C;
  int ubase=zz*MULZ+uc*CHZ;
  int uOff2=uc*(CHZ/2);
  unsigned int hreg[EB][6];
  #pragma unroll
  for(int e=0;e<EB;++e){
    #pragma unroll
    for(int r=0;r<6;++r) hreg[e][r]=hb[(size_t)(e0+e)*6+r];
  }
  const uint4* s_xp4=(const uint4*)s_xp;
  if(NL==1){
    if(g==0)      conv_main<MUL,C,EB,NL,USPLIT,1,1>(W2h,nW,hreg,s_xp4,s_B,s_red,s_msg,msg,la,g,e0,w,uc,ubase,uOff2);
    else if(g==1) conv_main<MUL,C,EB,NL,USPLIT,3,1>(W2h,nW,hreg,s_xp4,s_B,s_red,s_msg,msg,la,g,e0,w,uc,ubase,uOff2);
    else          conv_main<MUL,C,EB,NL,USPLIT,5,1>(W2h,nW,hreg,s_xp4,s_B,s_red,s_msg,msg,la,g,e0,w,uc,ubase,uOff2);
  }else{
    if(g==0)      conv_main<MUL,C,EB,NL,USPLIT,1,3>(W2h,nW,hreg,s_xp4,s_B,s_red,s_msg,msg,la,g,e0,w,uc,ubase,uOff2);
    else if(g==1) conv_main<MUL,C,EB,NL,USPLIT,3,4>(W2h,nW,hreg,s_xp4,s_B,s_red,s_msg,msg,la,g,e0,w,uc,ubase,uOff2);
    else          conv_main<MUL,C,EB,NL,USPLIT,5,4>(W2h,nW,hreg,s_xp4,s_B,s_red,s_msg,msg,la,g,e0,w,uc,ubase,uOff2);
  }
}

// ================= fused aggregate + pnorm + SI + nonlin -> packed f16 =================
template<int MUL>
__global__ void agg_post_kernel(const unsigned int* __restrict__ msg0,
                                const unsigned int* __restrict__ msg1,
                                const int* __restrict__ coff, const int* __restrict__ list,
                                const float* __restrict__ siw, const float* __restrict__ nlb,
                                unsigned int* __restrict__ xh){
  constexpr int W32=MUL*9/2;
  constexpr int ROW=9*MUL/2;
  __shared__ float s_in[MUL*9];
  __shared__ unsigned short s_out[MUL*9];
  __shared__ float red[256];
  int n=blockIdx.x, tid=threadIdx.x;
  int b=coff[n], en=coff[n+1];
  float ss=0.f;
  for(int c32=tid;c32<W32;c32+=256){
    float a0=0.f,a1=0.f;
    for(int j=b;j<en;++j){
      size_t o=(size_t)list[j]*W32+c32;
      half2v p=u2h2(msg0[o]); a0+=(float)p.x; a1+=(float)p.y;
      if(msg1){ half2v q=u2h2(msg1[o]); a0+=(float)q.x; a1+=(float)q.y; }
    }
    s_in[2*c32]=a0; s_in[2*c32+1]=a1;
    ss+=a0*a0+a1*a1;
  }
  red[tid]=ss; __syncthreads();
  for(int d=128;d>0;d>>=1){ if(tid<d) red[tid]+=red[tid+d]; __syncthreads(); }
  float scale=1.f/(sqrtf(red[0])+1e-6f);
  const float inv=scale/sqrtf((float)MUL);
  float b0=nlb[0], b1=nlb[1], b2=nlb[2];
  for(int p=tid;p<3*MUL;p+=256){
    int l=p/MUL, wo=p%MUL;
    if(l==0){
      const float* Wl=siw;
      float a=0.f;
      for(int u=0;u<MUL;++u) a+=s_in[u]*Wl[(size_t)u*MUL+wo];
      s_out[wo]=f2h(softplusf(a*inv+b0));
    } else if(l==1){
      const float* Wl=siw+(size_t)MUL*MUL;
      float v0=0.f,v1=0.f,v2=0.f;
      for(int u=0;u<MUL;++u){
        float wv=Wl[(size_t)u*MUL+wo];
        int bi=MUL+u*3;
        v0+=s_in[bi]*wv; v1+=s_in[bi+1]*wv; v2+=s_in[bi+2]*wv;
      }
      v0*=inv; v1*=inv; v2*=inv;
      float gate=softplusf(sqrtf(v0*v0+v1*v1+v2*v2+1e-24f)+b1);
      int ob=MUL+wo*3;
      s_out[ob]=f2h(v0*gate); s_out[ob+1]=f2h(v1*gate); s_out[ob+2]=f2h(v2*gate);
    } else {
      const float* Wl=siw+(size_t)2*MUL*MUL;
      float v0=0.f,v1=0.f,v2=0.f,v3=0.f,v4=0.f;
      for(int u=0;u<MUL;++u){
        float wv=Wl[(size_t)u*MUL+wo];
        int bi=4*MUL+u*5;
        v0+=s_in[bi]*wv; v1+=s_in[bi+1]*wv; v2+=s_in[bi+2]*wv; v3+=s_in[bi+3]*wv; v4+=s_in[bi+4]*wv;
      }
      v0*=inv; v1*=inv; v2*=inv; v3*=inv; v4*=inv;
      float gate=softplusf(sqrtf(v0*v0+v1*v1+v2*v2+v3*v3+v4*v4+1e-24f)+b2);
      int ob=4*MUL+wo*5;
      s_out[ob]=f2h(v0*gate); s_out[ob+1]=f2h(v1*gate); s_out[ob+2]=f2h(v2*gate);
      s_out[ob+3]=f2h(v3*gate); s_out[ob+4]=f2h(v4*gate);
    }
  }
  __syncthreads();
  for(int p=tid;p<ROW;p+=256){
    int l,i,u2;
    if(p<MUL/2){l=0;i=0;u2=p;}
    else if(p<2*MUL){int t=p-MUL/2;i=t/(MUL/2);u2=t%(MUL/2);l=1;}
    else{int t=p-2*MUL;i=t/(MUL/2);u2=t%(MUL/2);l=2;}
    int d=2*l+1, sb=MUL*l*l;
    unsigned short a=s_out[sb+(2*u2)*d+i], bb=s_out[sb+(2*u2+1)*d+i];
    xh[(size_t)n*ROW+p]=((unsigned int)bb<<16)|a;
  }
}

// ================= final l=0 self interaction =================
__global__ void final_kernel(const unsigned int* __restrict__ xh, const float* __restrict__ fsi,
                             float* __restrict__ out){
  int gid=blockIdx.x*blockDim.x+threadIdx.x;
  if(gid>=NNODES*32) return;
  int n=gid/32, wo=gid%32;
  float s=0.f;
  for(int u2=0;u2<16;++u2){
    half2v p=u2h2(xh[(size_t)n*144+u2]);
    s += (float)p.x*fsi[(2*u2)*32+wo] + (float)p.y*fsi[(2*u2+1)*32+wo];
  }
  out[gid]=s*(1.f/sqrtf(32.f));
}

// ================= host =================
static int w3off_of(int l1,int l2,int l3){
  const int L1[11]={0,0,0,1,1,1,1,2,2,2,2};
  const int L2[11]={0,1,2,0,1,1,2,0,1,2,2};
  const int L3[11]={0,1,2,1,0,2,1,2,1,0,2};
  const int OFF[11]={0,1,10,35,44,53,98,143,168,213,238};
  for(int i=0;i<11;++i) if(L1[i]==l1&&L2[i]==l2&&L3[i]==l3) return OFF[i];
  return 0;
}

static void fill_map(LayerArg& la, const int alloc[3]){
  int x=0;
  for(int g=0;g<3;++g){
    la.nxg[g]=alloc[g];
    for(int r=0;r<alloc[g];++r){ la.gOf[x]=g; la.rank[x]=r; ++x; }
  }
}
static int gridS(const int alloc[3], int NBZ){
  int S=0;
  for(int g=0;g<3;++g){ int s=(NBZ+alloc[g]-1)/alloc[g]; if(s>S)S=s; }
  return S;
}

extern "C" void kernel_launch(void* const* d_in, const int* in_sizes, int n_in,
                              void* d_out, int out_size, void* d_ws, size_t ws_size,
                              hipStream_t stream) {
  const float* pos    = (const float*)d_in[0];
  const float* feat   = (const float*)d_in[1];
  const int*   ei     = (const int*)d_in[2];
  const float* si0w   = (const float*)d_in[3];
  const float* c1_rw1 = (const float*)d_in[4];
  const float* c1_rw2 = (const float*)d_in[5];
  const float* si1w   = (const float*)d_in[6];
  const float* nl1b   = (const float*)d_in[7];
  const float* c2_rw1 = (const float*)d_in[8];
  const float* c2_rw2 = (const float*)d_in[9];
  const float* si2w   = (const float*)d_in[10];
  const float* nl2b   = (const float*)d_in[11];
  const float* c3_rw1 = (const float*)d_in[12];
  const float* c3_rw2 = (const float*)d_in[13];
  const float* si3w   = (const float*)d_in[14];
  const float* nl3b   = (const float*)d_in[15];
  const float* fsiw   = (const float*)d_in[16];

  float* ws_f=(float*)d_ws;
  float* w3   = ws_f+OFF_W3J;
  float* sh   = ws_f+OFF_SH;
  unsigned int* h1   = (unsigned int*)(ws_f+OFF_H1);
  unsigned int* h2   = (unsigned int*)(ws_f+OFF_H2);
  unsigned int* h3   = (unsigned int*)(ws_f+OFF_H3);
  unsigned int* w2p1 = (unsigned int*)(ws_f+OFF_W2P1);
  unsigned int* w2p2 = (unsigned int*)(ws_f+OFF_W2P2);
  unsigned int* w2p3 = (unsigned int*)(ws_f+OFF_W2P3);
  unsigned int* xh   = (unsigned int*)(ws_f+OFF_XH);
  unsigned int* msgA = (unsigned int*)(ws_f+OFF_MSGA);
  unsigned int* msgB = (unsigned int*)(ws_f+OFF_MSGB);
  unsigned int* V    = msgB;           // V shares msgB region (disjoint lifetime)
  int* cnt    = (int*)(ws_f+OFF_CNT);
  int* coff   = (int*)(ws_f+OFF_COFF);
  int* clist  = (int*)(ws_f+OFF_LIST);
  int* rankA  = (int*)(ws_f+OFF_RANK);
  const int* src  = ei;
  const int* dstp = ei+NEDGES;

  const bool split = ws_size >= WS_NEED_SPLIT;
  const int NB = NEDGES/4;

  LayerArg la1{}, la2{}, la3{};
  {
    int step=128*128;
    for(int i=0;i<3;++i){
      CInstr I{0,i,i, i*step, w3off_of(0,i,i), (float)std::sqrt((2.0*i+1.0)/128.0)};
      la1.ins[i][la1.cnt[i]++]=I;
    }
  }
  const int insL[11][3]={{0,0,0},{0,1,1},{0,2,2},{1,0,1},{1,1,0},{1,1,2},{1,2,1},{2,0,2},{2,1,1},{2,2,0},{2,2,2}};
  auto build=[&](LayerArg& la, int mul, int Cc){
    int step=mul*Cc;
    int fan[3]={0,0,0};
    for(int i=0;i<11;++i) fan[insL[i][2]] += mul;
    for(int i=0;i<11;++i){
      int l1v=insL[i][0],l2v=insL[i][1],l3v=insL[i][2];
      CInstr I{l1v,l2v,l3v, i*step, w3off_of(l1v,l2v,l3v), (float)std::sqrt((2.0*l3v+1.0)/(double)fan[l3v])};
      la.ins[l3v][la.cnt[l3v]++]=I;
    }
  };
  build(la2,128,64);
  build(la3,64,32);

  const int alloc1[3]={3,3,2};
  const int alloc23[3]={2,3,3};
  fill_map(la1,alloc1);
  fill_map(la2,alloc23);
  fill_map(la3,alloc23);

  w3j_kernel<<<dim3(11),dim3(128),0,stream>>>(w3);
  edge_prep_kernel<<<dim3(NEDGES/256),dim3(256),0,stream>>>(pos,ei,c1_rw1,c2_rw1,c3_rw1, sh,h1,h2,h3);
  if(split){
    w1pack_kernel<<<dim3((384*768+255)/256),dim3(256),0,stream>>>(c1_rw2,w2p1);
  } else {
    w2pack_kernel<<<dim3((6*49152+255)/256),dim3(256),0,stream>>>(c1_rw2,w2p1,49152);
  }
  w2pack_kernel<<<dim3((6*90112+255)/256),dim3(256),0,stream>>>(c2_rw2,w2p2,90112);
  w2pack_kernel<<<dim3((6*22528+255)/256),dim3(256),0,stream>>>(c3_rw2,w2p3,22528);

  hipMemsetAsync(cnt,0,NNODES*sizeof(int),stream);
  csr_rank_kernel<<<dim3(NEDGES/256),dim3(256),0,stream>>>(src,cnt,rankA);
  csr_scan_kernel<<<dim3(1),dim3(NNODES),0,stream>>>(cnt,coff);
  csr_scatter_kernel<<<dim3(NEDGES/256),dim3(256),0,stream>>>(src,coff,rankA,clist);

  si0_kernel<<<dim3(NNODES),dim3(128),0,stream>>>(feat,si0w,xh);

  if(split){
    // layer 1: node-side GEMM + light edge pass
    vgemm1_kernel<<<dim3(NNODES/4),dim3(384),0,stream>>>(xh,w2p1,V);
    conv1_edge_kernel<<<dim3(NEDGES/2),dim3(384),0,stream>>>(V,h1,sh,dstp,w3,msgA);
    agg_post_kernel<128><<<dim3(NNODES),dim3(256),0,stream>>>(msgA,(const unsigned int*)nullptr,coff,clist,si1w,nl1b,xh);
    // layer 2: R7 g-partitioned conv, USPLIT=2
    int S23=gridS(alloc23,NB*2);
    conv_kernel<128,64,4,3,2><<<dim3(8*S23),dim3(256),0,stream>>>(xh,w2p2,90112,h2,sh,dstp,w3,msgA,msgB,la2);
    agg_post_kernel<64><<<dim3(NNODES),dim3(256),0,stream>>>(msgA,msgB,coff,clist,si2w,nl2b,xh);
    // layer 3: USPLIT=1
    int S3=gridS(alloc23,NB);
    conv_kernel<64,32,4,3,1><<<dim3(8*S3),dim3(256),0,stream>>>(xh,w2p3,22528,h3,sh,dstp,w3,msgA,msgA,la3);
    agg_post_kernel<32><<<dim3(NNODES),dim3(256),0,stream>>>(msgA,(const unsigned int*)nullptr,coff,clist,si3w,nl3b,xh);
  } else {
    int S1=gridS(alloc1,NB), S23=gridS(alloc23,NB);
    conv_kernel<128,128,4,1,1><<<dim3(8*S1),dim3(256),0,stream>>>(xh,w2p1,49152,h1,sh,dstp,w3,msgA,msgA,la1);
    agg_post_kernel<128><<<dim3(NNODES),dim3(256),0,stream>>>(msgA,(const unsigned int*)nullptr,coff,clist,si1w,nl1b,xh);
    conv_kernel<128,64,4,3,1><<<dim3(8*S23),dim3(256),0,stream>>>(xh,w2p2,90112,h2,sh,dstp,w3,msgA,msgA,la2);
    agg_post_kernel<64><<<dim3(NNODES),dim3(256),0,stream>>>(msgA,(const unsigned int*)nullptr,coff,clist,si2w,nl2b,xh);
    conv_kernel<64,32,4,3,1><<<dim3(8*S23),dim3(256),0,stream>>>(xh,w2p3,22528,h3,sh,dstp,w3,msgA,msgA,la3);
    agg_post_kernel<32><<<dim3(NNODES),dim3(256),0,stream>>>(msgA,(const unsigned int*)nullptr,coff,clist,si3w,nl3b,xh);
  }

  final_kernel<<<dim3((NNODES*32+255)/256),dim3(256),0,stream>>>(xh,fsiw,(float*)d_out);
}